// Round 8
// baseline (683.723 us; speedup 1.0000x reference)
//
#include <hip/hip_runtime.h>
#include <hip/hip_bf16.h>

typedef float f32x4 __attribute__((ext_vector_type(4)));
typedef short short8 __attribute__((ext_vector_type(8)));

#define NTOT   65536
#define DDIM   256
#define KCODES 1024
#define BRR    128          // z rows per block (vq_main)
#define CT     64           // codes per tile
#define IDXOFF 16777217     // 1 + NTOT*DDIM
#define MARGIN 0.04f        // bf16^3 score error bound ~0.019; 2x slack

// ws layout (fp32 elems):
//  [0..64) loss buckets | ((int*)ws)[64] cnt | [80..1104) wsq
//  [2048..264192) wplanes (64 tiles x 16KB, swizzled hi|lo images)
//  [264192..329728) list (flagged rows, int)

__device__ __forceinline__ unsigned short bf16_rne(float x) {
  unsigned u = __float_as_uint(x);
  return (unsigned short)((u + 0x7fff + ((u >> 16) & 1)) >> 16);
}

// ---------------- kernel 0: wsq[k] = ||w_k||^2 ----------------
__global__ __launch_bounds__(256) void wsq_kernel(const float* __restrict__ w,
                                                  float* __restrict__ wsq) {
  int k = blockIdx.x * 256 + threadIdx.x;
  if (k >= KCODES) return;
  const f32x4* wr = (const f32x4*)(w + (size_t)k * DDIM);
  float s = 0.f;
#pragma unroll 8
  for (int j = 0; j < DDIM / 4; ++j) {
    f32x4 v = wr[j];
    s += v[0] * v[0] + v[1] * v[1] + v[2] * v[2] + v[3] * v[3];
  }
  wsq[k] = s;
}

// ---------------- kernel 1: w -> hi/lo bf16 planes, tiled+swizzled ----------------
__global__ __launch_bounds__(256) void prep_w(const float* __restrict__ w,
                                              float* __restrict__ wplanes) {
  int t = blockIdx.x * 256 + threadIdx.x;
  int k = t >> 6;
  int d = (t & 63) * 4;
  f32x4 v = *(const f32x4*)(w + (size_t)k * DDIM + d);
  unsigned h[4], l[4];
#pragma unroll
  for (int j = 0; j < 4; ++j) {
    unsigned short hb = bf16_rne(v[j]);
    float hf = __uint_as_float(((unsigned)hb) << 16);
    h[j] = hb;
    l[j] = bf16_rne(v[j] - hf);
  }
  int ct = k >> 6, row = k & 63, dc = d >> 6, dloc = d & 63;
  size_t base = (size_t)(ct * 4 + dc) * 16384;
  int off = row * 128 + ((dloc * 2) ^ ((row & 7) << 4));
  *(int2*)((char*)wplanes + base + off) =
      make_int2((int)(h[0] | (h[1] << 16)), (int)(h[2] | (h[3] << 16)));
  *(int2*)((char*)wplanes + base + 8192 + off) =
      make_int2((int)(l[0] | (l[1] << 16)), (int)(l[2] | (l[3] << 16)));
}

// stage a [128 rows][64 d] fp32 z-chunk as hi/lo bf16 planes into LDS
__device__ __forceinline__ void stage_tile_z(const float* __restrict__ gsrc,
                                             short* hi_t, short* lo_t, int tid) {
#pragma unroll
  for (int it = 0; it < 8; ++it) {
    int flat4 = it * 256 + tid;
    int row = flat4 >> 4;
    int c4 = (flat4 & 15) * 4;
    f32x4 v = *(const f32x4*)(gsrc + (size_t)row * DDIM + c4);
    unsigned h[4], l[4];
#pragma unroll
    for (int j = 0; j < 4; ++j) {
      unsigned short hb = bf16_rne(v[j]);
      float hf = __uint_as_float(((unsigned)hb) << 16);
      h[j] = hb;
      l[j] = bf16_rne(v[j] - hf);
    }
    int off = row * 128 + ((c4 * 2) ^ ((row & 7) << 4));
    *(int2*)((char*)hi_t + off) = make_int2((int)(h[0] | (h[1] << 16)), (int)(h[2] | (h[3] << 16)));
    *(int2*)((char*)lo_t + off) = make_int2((int)(l[0] | (l[1] << 16)), (int)(l[2] | (l[3] << 16)));
  }
}

// async stage one 16KB w tile image: pre-swizzled global -> linear LDS
__device__ __forceinline__ void stage_w(const float* __restrict__ wpl, int st,
                                        char* buf, int tid) {
  const char* g = (const char*)wpl + (size_t)st * 16384 + tid * 16;
  char* l = buf + ((tid >> 6) << 10);  // wave-uniform base; HW adds lane*16
#pragma unroll
  for (int i = 0; i < 4; ++i)
    __builtin_amdgcn_global_load_lds(
        (const __attribute__((address_space(1))) unsigned int*)(g + i * 4096),
        (__attribute__((address_space(3))) unsigned int*)(l + i * 4096), 16, 0, 0);
}

#define MFMA_STEP(DC, TB)                                                   \
  {                                                                         \
    _Pragma("unroll")                                                       \
    for (int ks = 0; ks < 2; ++ks) {                                        \
      _Pragma("unroll")                                                     \
      for (int mi = 0; mi < 4; ++mi) {                                      \
        const int row = mi * 16 + l15;                                      \
        const int off = row * 128 + (((ks * 64) + (lg * 16)) ^ ((row & 7) << 4)); \
        short8 ah = *(const short8*)((TB) + off);                           \
        short8 al = *(const short8*)((TB) + 8192 + off);                    \
        acc[mi][0] = __builtin_amdgcn_mfma_f32_16x16x32_bf16(ah, zf[DC][ks][0][0], acc[mi][0], 0, 0, 0); \
        acc[mi][0] = __builtin_amdgcn_mfma_f32_16x16x32_bf16(ah, zf[DC][ks][0][1], acc[mi][0], 0, 0, 0); \
        acc[mi][0] = __builtin_amdgcn_mfma_f32_16x16x32_bf16(al, zf[DC][ks][0][0], acc[mi][0], 0, 0, 0); \
        acc[mi][1] = __builtin_amdgcn_mfma_f32_16x16x32_bf16(ah, zf[DC][ks][1][0], acc[mi][1], 0, 0, 0); \
        acc[mi][1] = __builtin_amdgcn_mfma_f32_16x16x32_bf16(ah, zf[DC][ks][1][1], acc[mi][1], 0, 0, 0); \
        acc[mi][1] = __builtin_amdgcn_mfma_f32_16x16x32_bf16(al, zf[DC][ks][1][0], acc[mi][1], 0, 0, 0); \
      }                                                                     \
    }                                                                       \
  }

// ---------------- kernel 2: MFMA argmin + fused gather/write/loss ----------------
__global__ __launch_bounds__(256, 2) void vq_main(
    const float* __restrict__ z, const float* __restrict__ w,
    const float* __restrict__ wplanes, const float* __restrict__ wsq,
    float* __restrict__ buckets, int* __restrict__ cnt, int* __restrict__ list,
    float* __restrict__ out) {
  __shared__ __align__(16) char lds[36864];  // buf0 16K | buf1 16K | wsq 4K
  char* buf0 = lds;
  char* buf1 = lds + 16384;
  float* wsq_l = (float*)(lds + 32768);
  __shared__ int sidx[BRR];
  __shared__ float ws4[4];

  const int tid = threadIdx.x;
  const int lane = tid & 63, wid = tid >> 6;
  const int l15 = lane & 15, lg = lane >> 4;
  const int br = blockIdx.x * BRR;

  for (int i = tid; i < KCODES; i += 256) wsq_l[i] = wsq[i];

  // ---- z fragments -> registers: zf[dc][ks][ni][plane] ----
  short8 zf[4][2][2][2];
  {
    short* zhi = (short*)lds;
    short* zlo = (short*)(lds + 16384);
    const int row0 = wid * 32 + l15, row1 = row0 + 16;
#pragma unroll
    for (int dc = 0; dc < 4; ++dc) {
      __syncthreads();
      stage_tile_z(z + (size_t)br * DDIM + dc * 64, zhi, zlo, tid);
      __syncthreads();
#pragma unroll
      for (int ks = 0; ks < 2; ++ks) {
        const int kb2 = (ks * 32 + lg * 8) * 2;
        const int off0 = row0 * 128 + (kb2 ^ ((row0 & 7) << 4));
        const int off1 = row1 * 128 + (kb2 ^ ((row1 & 7) << 4));
        zf[dc][ks][0][0] = *(const short8*)((char*)zhi + off0);
        zf[dc][ks][0][1] = *(const short8*)((char*)zlo + off0);
        zf[dc][ks][1][0] = *(const short8*)((char*)zhi + off1);
        zf[dc][ks][1][1] = *(const short8*)((char*)zlo + off1);
      }
    }
    __syncthreads();
  }

  // running (min1, idx, min2) per z-row (ni=0 -> row0, ni=1 -> row1)
  float m1[2] = {3.4e38f, 3.4e38f}, m2[2] = {3.4e38f, 3.4e38f};
  int i1[2] = {0x7fffffff, 0x7fffffff};

  // prologue: stage tile 0
  stage_w(wplanes, 0, buf0, tid);
  __syncthreads();

  for (int ct = 0; ct < 16; ++ct) {
    f32x4 acc[4][2];
#pragma unroll
    for (int mi = 0; mi < 4; ++mi)
#pragma unroll
      for (int ni = 0; ni < 2; ++ni) acc[mi][ni] = (f32x4){0.f, 0.f, 0.f, 0.f};

#pragma unroll
    for (int dc = 0; dc < 4; ++dc) {
      const int st = ct * 4 + dc;
      char* cbuf = (st & 1) ? buf1 : buf0;
      char* nbuf = (st & 1) ? buf0 : buf1;
      if (st < 63) stage_w(wplanes, st + 1, nbuf, tid);  // overlaps MFMA below
      MFMA_STEP(dc, cbuf)
      __syncthreads();
    }

    // epilogue: scores, running min1/min2 (codes ascend per lane -> first-tie wins)
    const int kb = ct * CT;
#pragma unroll
    for (int ni = 0; ni < 2; ++ni)
#pragma unroll
      for (int mi = 0; mi < 4; ++mi)
#pragma unroll
        for (int rg = 0; rg < 4; ++rg) {
          const int cg = kb + mi * 16 + lg * 4 + rg;
          float s = fmaf(-2.f, acc[mi][ni][rg], wsq_l[cg]);
          if (s < m1[ni]) { m2[ni] = m1[ni]; m1[ni] = s; i1[ni] = cg; }
          else if (s < m2[ni]) m2[ni] = s;
        }
  }

  // ---- cross-lane merge over the 4 k-groups (xor 16, 32), idx tie -> lower ----
#pragma unroll
  for (int ni = 0; ni < 2; ++ni) {
#pragma unroll
    for (int m = 16; m <= 32; m <<= 1) {
      float om1 = __shfl_xor(m1[ni], m);
      float om2 = __shfl_xor(m2[ni], m);
      int oi1 = __shfl_xor(i1[ni], m);
      if (om1 < m1[ni] || (om1 == m1[ni] && oi1 < i1[ni])) {
        m2[ni] = fminf(m1[ni], om2); m1[ni] = om1; i1[ni] = oi1;
      } else {
        m2[ni] = fminf(m2[ni], om1);
      }
    }
  }

  if (lg == 0) {
#pragma unroll
    for (int ni = 0; ni < 2; ++ni) {
      int rl = wid * 32 + ni * 16 + l15;
      int grow = br + rl;
      sidx[rl] = i1[ni];
      out[(size_t)IDXOFF + grow] = (float)i1[ni];  // provisional for flagged rows
      if (m2[ni] - m1[ni] < MARGIN) { int p = atomicAdd(cnt, 1); list[p] = grow; }
    }
  }
  __syncthreads();

  // ---- fused: gather z_q, write z_q_st = z + (z_q - z), accumulate loss ----
  float lsum = 0.f;
  for (int r = 0; r < BRR; ++r) {
    int idx = sidx[r];
    float qv = w[(size_t)idx * DDIM + tid];
    float zv = z[(size_t)(br + r) * DDIM + tid];
    float df = qv - zv;
    out[1 + (size_t)(br + r) * DDIM + tid] = zv + df;
    lsum = fmaf(df, df, lsum);
  }
#pragma unroll
  for (int m = 32; m > 0; m >>= 1) lsum += __shfl_down(lsum, m, 64);
  if (lane == 0) ws4[wid] = lsum;
  __syncthreads();
  if (tid == 0)
    atomicAdd(&buckets[blockIdx.x & 63], ws4[0] + ws4[1] + ws4[2] + ws4[3]);
}

// ---------------- kernel 3: exact full rescan for flagged rows, patch + loss delta ----------------
__global__ __launch_bounds__(256) void patch(
    const float* __restrict__ z, const float* __restrict__ w,
    const float* __restrict__ wsq, float* __restrict__ buckets,
    const int* __restrict__ cnt, const int* __restrict__ list,
    float* __restrict__ out) {
  __shared__ __align__(16) float zrow[DDIM];
  __shared__ float rv[256];
  __shared__ int ri[256];
  const int tid = threadIdx.x;
  const int n = *cnt;
  for (int li = blockIdx.x; li < n; li += gridDim.x) {
    const int row = list[li];
    __syncthreads();
    zrow[tid] = z[(size_t)row * DDIM + tid];
    __syncthreads();
    float bv = 3.4e38f; int bi = 0;
#pragma unroll
    for (int c0 = 0; c0 < 4; ++c0) {
      int c = tid * 4 + c0;
      const f32x4* wr4 = (const f32x4*)(w + (size_t)c * DDIM);
      const f32x4* zr4 = (const f32x4*)zrow;
      f32x4 dv = {0.f, 0.f, 0.f, 0.f};
      for (int q = 0; q < DDIM / 4; ++q) {
        f32x4 a = zr4[q], b = wr4[q];
        dv[0] = fmaf(a[0], b[0], dv[0]); dv[1] = fmaf(a[1], b[1], dv[1]);
        dv[2] = fmaf(a[2], b[2], dv[2]); dv[3] = fmaf(a[3], b[3], dv[3]);
      }
      float s = fmaf(-2.f, (dv[0] + dv[1]) + (dv[2] + dv[3]), wsq[c]);
      if (s < bv) { bv = s; bi = c; }   // c ascending per thread -> first-tie wins
    }
    rv[tid] = bv; ri[tid] = bi;
    __syncthreads();
    for (int s = 128; s > 0; s >>= 1) {
      if (tid < s) {
        float v2 = rv[tid + s]; int i2 = ri[tid + s];
        if (v2 < rv[tid] || (v2 == rv[tid] && i2 < ri[tid])) { rv[tid] = v2; ri[tid] = i2; }
      }
      __syncthreads();
    }
    const int idx = ri[0];
    const int old = (int)out[(size_t)IDXOFF + row];
    if (tid == 0) out[(size_t)IDXOFF + row] = (float)idx;
    // rewrite z_q_st and accumulate loss delta (new - old)
    float zv = zrow[tid];
    float dfn = w[(size_t)idx * DDIM + tid] - zv;
    float dfo = w[(size_t)old * DDIM + tid] - zv;
    out[1 + (size_t)row * DDIM + tid] = zv + dfn;
    __syncthreads();
    rv[tid] = dfn * dfn - dfo * dfo;
    __syncthreads();
    for (int s = 128; s > 0; s >>= 1) {
      if (tid < s) rv[tid] += rv[tid + s];
      __syncthreads();
    }
    if (tid == 0) atomicAdd(&buckets[row & 63], rv[0]);
  }
}

// ---------------- kernel 4: finalize loss ----------------
__global__ void vq_finalize(const float* __restrict__ buckets,
                            float* __restrict__ out) {
  float s = 0.f;
  for (int i = 0; i < 64; ++i) s += buckets[i];
  out[0] = 0.25f * s * (1.0f / 16777216.0f);
}

extern "C" void kernel_launch(void* const* d_in, const int* in_sizes, int n_in,
                              void* d_out, int out_size, void* d_ws, size_t ws_size,
                              hipStream_t stream) {
  const float* z = (const float*)d_in[0];
  const float* w = (const float*)d_in[1];
  float* out = (float*)d_out;
  float* wsf = (float*)d_ws;
  float* buckets = wsf;
  int* cnt = (int*)wsf + 64;
  float* wsq = wsf + 80;
  float* wplanes = wsf + 2048;
  int* list = (int*)(wsf + 264192);

  hipMemsetAsync(d_ws, 0, 320, stream);  // buckets + cnt
  wsq_kernel<<<dim3(KCODES / 256), dim3(256), 0, stream>>>(w, wsq);
  prep_w<<<dim3(256), dim3(256), 0, stream>>>(w, wplanes);
  vq_main<<<dim3(NTOT / BRR), dim3(256), 0, stream>>>(z, w, wplanes, wsq, buckets, cnt, list, out);
  patch<<<dim3(1024), dim3(256), 0, stream>>>(z, w, wsq, buckets, cnt, list, out);
  vq_finalize<<<dim3(1), dim3(1), 0, stream>>>(buckets, out);
}

// Round 9
// 289.776 us; speedup vs baseline: 2.3595x; 2.3595x over previous
//
#include <hip/hip_runtime.h>
#include <hip/hip_bf16.h>

typedef float f32x4 __attribute__((ext_vector_type(4)));
typedef short short8 __attribute__((ext_vector_type(8)));

#define NTOT   65536
#define DDIM   256
#define KCODES 1024
#define BRR    128          // z rows per block (vq_main)
#define CT     64           // codes per tile
#define IDXOFF 16777217     // 1 + NTOT*DDIM
#define MARGIN 0.05f        // worst-case bf16^3 score error 2*eps ~ 0.032 < 0.05

// ws layout (fp32 elems):
//  [0..64) loss buckets | ((int*)ws)[64] cnt, [65] cnt2 | [80..1104) wsq
//  [2048..264192)   wplanes (64 tiles x 16KB, swizzled hi|lo images)
//  [264192..526336) cand (65536 x int4; .x == -1 => full_scan owns row)
//  [526336..591872) list  (pair-flagged rows)
//  [591872..657408) list2 (full-scan rows)

__device__ __forceinline__ unsigned short bf16_rne(float x) {
  unsigned u = __float_as_uint(x);
  return (unsigned short)((u + 0x7fff + ((u >> 16) & 1)) >> 16);
}

// ---------------- kernel 0: wsq[k] = ||w_k||^2 ----------------
__global__ __launch_bounds__(256) void wsq_kernel(const float* __restrict__ w,
                                                  float* __restrict__ wsq) {
  int k = blockIdx.x * 256 + threadIdx.x;
  if (k >= KCODES) return;
  const f32x4* wr = (const f32x4*)(w + (size_t)k * DDIM);
  float s = 0.f;
#pragma unroll 8
  for (int j = 0; j < DDIM / 4; ++j) {
    f32x4 v = wr[j];
    s += v[0] * v[0] + v[1] * v[1] + v[2] * v[2] + v[3] * v[3];
  }
  wsq[k] = s;
}

// ---------------- kernel 1: w -> hi/lo bf16 planes, tiled+swizzled ----------------
__global__ __launch_bounds__(256) void prep_w(const float* __restrict__ w,
                                              float* __restrict__ wplanes) {
  int t = blockIdx.x * 256 + threadIdx.x;
  int k = t >> 6;
  int d = (t & 63) * 4;
  f32x4 v = *(const f32x4*)(w + (size_t)k * DDIM + d);
  unsigned h[4], l[4];
#pragma unroll
  for (int j = 0; j < 4; ++j) {
    unsigned short hb = bf16_rne(v[j]);
    float hf = __uint_as_float(((unsigned)hb) << 16);
    h[j] = hb;
    l[j] = bf16_rne(v[j] - hf);
  }
  int ct = k >> 6, row = k & 63, dc = d >> 6, dloc = d & 63;
  size_t base = (size_t)(ct * 4 + dc) * 16384;
  int off = row * 128 + ((dloc * 2) ^ ((row & 7) << 4));
  *(int2*)((char*)wplanes + base + off) =
      make_int2((int)(h[0] | (h[1] << 16)), (int)(h[2] | (h[3] << 16)));
  *(int2*)((char*)wplanes + base + 8192 + off) =
      make_int2((int)(l[0] | (l[1] << 16)), (int)(l[2] | (l[3] << 16)));
}

// stage a [128 rows][64 d] fp32 z-chunk as hi/lo bf16 planes into LDS
__device__ __forceinline__ void stage_tile_z(const float* __restrict__ gsrc,
                                             short* hi_t, short* lo_t, int tid) {
#pragma unroll
  for (int it = 0; it < 8; ++it) {
    int flat4 = it * 256 + tid;
    int row = flat4 >> 4;
    int c4 = (flat4 & 15) * 4;
    f32x4 v = *(const f32x4*)(gsrc + (size_t)row * DDIM + c4);
    unsigned h[4], l[4];
#pragma unroll
    for (int j = 0; j < 4; ++j) {
      unsigned short hb = bf16_rne(v[j]);
      float hf = __uint_as_float(((unsigned)hb) << 16);
      h[j] = hb;
      l[j] = bf16_rne(v[j] - hf);
    }
    int off = row * 128 + ((c4 * 2) ^ ((row & 7) << 4));
    *(int2*)((char*)hi_t + off) = make_int2((int)(h[0] | (h[1] << 16)), (int)(h[2] | (h[3] << 16)));
    *(int2*)((char*)lo_t + off) = make_int2((int)(l[0] | (l[1] << 16)), (int)(l[2] | (l[3] << 16)));
  }
}

// async stage one 16KB w tile image: pre-swizzled global -> linear LDS
__device__ __forceinline__ void stage_w(const float* __restrict__ wpl, int st,
                                        char* buf, int tid) {
  const char* g = (const char*)wpl + (size_t)st * 16384 + tid * 16;
  char* l = buf + ((tid >> 6) << 10);  // wave-uniform base; HW adds lane*16
#pragma unroll
  for (int i = 0; i < 4; ++i)
    __builtin_amdgcn_global_load_lds(
        (const __attribute__((address_space(1))) unsigned int*)(g + i * 4096),
        (__attribute__((address_space(3))) unsigned int*)(l + i * 4096), 16, 0, 0);
}

#define INS4(S0, S1, S2, S3, I0, I1, I2, I3, os, oi)                        \
  if (os < S3 || (os == S3 && oi < I3)) {                                   \
    if (os < S2 || (os == S2 && oi < I2)) {                                 \
      S3 = S2; I3 = I2;                                                     \
      if (os < S1 || (os == S1 && oi < I1)) {                               \
        S2 = S1; I2 = I1;                                                   \
        if (os < S0 || (os == S0 && oi < I0)) {                             \
          S1 = S0; I1 = I0; S0 = os; I0 = oi;                               \
        } else { S1 = os; I1 = oi; }                                        \
      } else { S2 = os; I2 = oi; }                                          \
    } else { S3 = os; I3 = oi; }                                            \
  }

#define MFMA_STEP(DC, TB)                                                   \
  {                                                                         \
    _Pragma("unroll")                                                       \
    for (int ks = 0; ks < 2; ++ks) {                                        \
      _Pragma("unroll")                                                     \
      for (int mi = 0; mi < 4; ++mi) {                                      \
        const int row = mi * 16 + l15;                                      \
        const int off = row * 128 + (((ks * 64) + (lg * 16)) ^ ((row & 7) << 4)); \
        short8 ah = *(const short8*)((TB) + off);                           \
        short8 al = *(const short8*)((TB) + 8192 + off);                    \
        acc[mi][0] = __builtin_amdgcn_mfma_f32_16x16x32_bf16(ah, zf[DC][ks][0][0], acc[mi][0], 0, 0, 0); \
        acc[mi][0] = __builtin_amdgcn_mfma_f32_16x16x32_bf16(ah, zf[DC][ks][0][1], acc[mi][0], 0, 0, 0); \
        acc[mi][0] = __builtin_amdgcn_mfma_f32_16x16x32_bf16(al, zf[DC][ks][0][0], acc[mi][0], 0, 0, 0); \
        acc[mi][1] = __builtin_amdgcn_mfma_f32_16x16x32_bf16(ah, zf[DC][ks][1][0], acc[mi][1], 0, 0, 0); \
        acc[mi][1] = __builtin_amdgcn_mfma_f32_16x16x32_bf16(ah, zf[DC][ks][1][1], acc[mi][1], 0, 0, 0); \
        acc[mi][1] = __builtin_amdgcn_mfma_f32_16x16x32_bf16(al, zf[DC][ks][1][0], acc[mi][1], 0, 0, 0); \
      }                                                                     \
    }                                                                       \
  }

// ---------------- kernel 2: MFMA top-4 + fused gather/write/loss ----------------
__global__ __launch_bounds__(256, 2) void vq_main(
    const float* __restrict__ z, const float* __restrict__ w,
    const float* __restrict__ wplanes, const float* __restrict__ wsq,
    float* __restrict__ buckets, int* __restrict__ cnt, int* __restrict__ cnt2,
    int* __restrict__ list, int* __restrict__ list2, int* __restrict__ cand,
    float* __restrict__ out) {
  __shared__ __align__(16) char lds[36864];  // buf0 16K | buf1 16K | wsq 4K
  char* buf0 = lds;
  char* buf1 = lds + 16384;
  float* wsq_l = (float*)(lds + 32768);
  __shared__ int sidx[BRR];
  __shared__ float ws4[4];

  const int tid = threadIdx.x;
  const int lane = tid & 63, wid = tid >> 6;
  const int l15 = lane & 15, lg = lane >> 4;
  const int br = blockIdx.x * BRR;

  for (int i = tid; i < KCODES; i += 256) wsq_l[i] = wsq[i];

  // ---- z fragments -> registers: zf[dc][ks][ni][plane] ----
  short8 zf[4][2][2][2];
  {
    short* zhi = (short*)lds;
    short* zlo = (short*)(lds + 16384);
    const int row0 = wid * 32 + l15, row1 = row0 + 16;
#pragma unroll
    for (int dc = 0; dc < 4; ++dc) {
      __syncthreads();
      stage_tile_z(z + (size_t)br * DDIM + dc * 64, zhi, zlo, tid);
      __syncthreads();
#pragma unroll
      for (int ks = 0; ks < 2; ++ks) {
        const int kb2 = (ks * 32 + lg * 8) * 2;
        const int off0 = row0 * 128 + (kb2 ^ ((row0 & 7) << 4));
        const int off1 = row1 * 128 + (kb2 ^ ((row1 & 7) << 4));
        zf[dc][ks][0][0] = *(const short8*)((char*)zhi + off0);
        zf[dc][ks][0][1] = *(const short8*)((char*)zlo + off0);
        zf[dc][ks][1][0] = *(const short8*)((char*)zhi + off1);
        zf[dc][ks][1][1] = *(const short8*)((char*)zlo + off1);
      }
    }
    __syncthreads();
  }

  // top-4 per z-row (ni=0: a/e, ni=1: c/f), sorted by (score, idx)
  float a0 = 3.4e38f, a1 = 3.4e38f, a2 = 3.4e38f, a3 = 3.4e38f;
  int e0 = 0x7fffffff, e1 = 0x7fffffff, e2 = 0x7fffffff, e3 = 0x7fffffff;
  float c0 = 3.4e38f, c1 = 3.4e38f, c2 = 3.4e38f, c3 = 3.4e38f;
  int f0 = 0x7fffffff, f1 = 0x7fffffff, f2 = 0x7fffffff, f3 = 0x7fffffff;

  // prologue: stage tile 0
  stage_w(wplanes, 0, buf0, tid);
  __syncthreads();

  for (int ct = 0; ct < 16; ++ct) {
    f32x4 acc[4][2];
#pragma unroll
    for (int mi = 0; mi < 4; ++mi)
#pragma unroll
      for (int ni = 0; ni < 2; ++ni) acc[mi][ni] = (f32x4){0.f, 0.f, 0.f, 0.f};

#pragma unroll
    for (int dc = 0; dc < 4; ++dc) {
      const int st = ct * 4 + dc;
      char* cbuf = (st & 1) ? buf1 : buf0;
      char* nbuf = (st & 1) ? buf0 : buf1;
      if (st < 63) stage_w(wplanes, st + 1, nbuf, tid);  // overlaps MFMA below
      MFMA_STEP(dc, cbuf)
      __syncthreads();
    }

    // epilogue: guarded top-4 insertion (most scores fail the 4th-best test)
    const int kb = ct * CT;
#pragma unroll
    for (int mi = 0; mi < 4; ++mi)
#pragma unroll
      for (int rg = 0; rg < 4; ++rg) {
        const int cg = kb + mi * 16 + lg * 4 + rg;
        const float w2 = wsq_l[cg];
        float s0v = fmaf(-2.f, acc[mi][0][rg], w2);
        if (s0v < a3 || (s0v == a3 && cg < e3)) { INS4(a0, a1, a2, a3, e0, e1, e2, e3, s0v, cg); }
        float s1v = fmaf(-2.f, acc[mi][1][rg], w2);
        if (s1v < c3 || (s1v == c3 && cg < f3)) { INS4(c0, c1, c2, c3, f0, f1, f2, f3, s1v, cg); }
      }
  }

  // ---- cross-lane merge of top-4 over the 4 k-groups (xor 16, 32) ----
#pragma unroll
  for (int m = 16; m <= 32; m <<= 1) {
    float os[4]; int oi[4];
    os[0] = __shfl_xor(a0, m); oi[0] = __shfl_xor(e0, m);
    os[1] = __shfl_xor(a1, m); oi[1] = __shfl_xor(e1, m);
    os[2] = __shfl_xor(a2, m); oi[2] = __shfl_xor(e2, m);
    os[3] = __shfl_xor(a3, m); oi[3] = __shfl_xor(e3, m);
#pragma unroll
    for (int t = 0; t < 4; ++t) { INS4(a0, a1, a2, a3, e0, e1, e2, e3, os[t], oi[t]); }
    os[0] = __shfl_xor(c0, m); oi[0] = __shfl_xor(f0, m);
    os[1] = __shfl_xor(c1, m); oi[1] = __shfl_xor(f1, m);
    os[2] = __shfl_xor(c2, m); oi[2] = __shfl_xor(f2, m);
    os[3] = __shfl_xor(c3, m); oi[3] = __shfl_xor(f3, m);
#pragma unroll
    for (int t = 0; t < 4; ++t) { INS4(c0, c1, c2, c3, f0, f1, f2, f3, os[t], oi[t]); }
  }

  if (lg == 0) {
    {
      int rl = wid * 32 + l15;
      int grow = br + rl;
      sidx[rl] = e0;
      out[(size_t)IDXOFF + grow] = (float)e0;  // provisional
      if (a1 - a0 < MARGIN) {
        bool needfull = (a3 - a0 < MARGIN);
        *(int4*)&cand[(size_t)grow * 4] = make_int4(needfull ? -1 : e0, e1, e2, e3);
        int p = atomicAdd(cnt, 1); list[p] = grow;
        if (needfull) { int q = atomicAdd(cnt2, 1); list2[q] = grow; }
      }
    }
    {
      int rl = wid * 32 + 16 + l15;
      int grow = br + rl;
      sidx[rl] = f0;
      out[(size_t)IDXOFF + grow] = (float)f0;  // provisional
      if (c1 - c0 < MARGIN) {
        bool needfull = (c3 - c0 < MARGIN);
        *(int4*)&cand[(size_t)grow * 4] = make_int4(needfull ? -1 : f0, f1, f2, f3);
        int p = atomicAdd(cnt, 1); list[p] = grow;
        if (needfull) { int q = atomicAdd(cnt2, 1); list2[q] = grow; }
      }
    }
  }
  __syncthreads();

  // ---- fused: gather z_q, write z_q_st = z + (z_q - z), accumulate loss ----
  float lsum = 0.f;
  for (int r = 0; r < BRR; ++r) {
    int idx = sidx[r];
    float qv = w[(size_t)idx * DDIM + tid];
    float zv = z[(size_t)(br + r) * DDIM + tid];
    float df = qv - zv;
    out[1 + (size_t)(br + r) * DDIM + tid] = zv + df;
    lsum = fmaf(df, df, lsum);
  }
#pragma unroll
  for (int m = 32; m > 0; m >>= 1) lsum += __shfl_down(lsum, m, 64);
  if (lane == 0) ws4[wid] = lsum;
  __syncthreads();
  if (tid == 0)
    atomicAdd(&buckets[blockIdx.x & 63], ws4[0] + ws4[1] + ws4[2] + ws4[3]);
}

// ---------------- kernel 3: exact re-rank of top-4 for pair-flagged rows ----------------
__global__ __launch_bounds__(256) void patch_lite(
    const float* __restrict__ z, const float* __restrict__ w,
    const float* __restrict__ wsq, const int* __restrict__ cnt,
    const int* __restrict__ list, const int* __restrict__ cand,
    float* __restrict__ buckets, float* __restrict__ out) {
  const int tid = threadIdx.x, lane = tid & 63, wv = tid >> 6;
  const int n = *cnt;
  float dloss = 0.f;
  for (int li = blockIdx.x * 4 + wv; li < n; li += gridDim.x * 4) {
    const int r = list[li];
    const int4 c4 = *(const int4*)&cand[(size_t)r * 4];
    if (c4.x < 0) continue;  // full_scan owns
    f32x4 zv = *(const f32x4*)(z + (size_t)r * DDIM + lane * 4);
    f32x4 w0 = *(const f32x4*)(w + (size_t)c4.x * DDIM + lane * 4);
    f32x4 w1 = *(const f32x4*)(w + (size_t)c4.y * DDIM + lane * 4);
    f32x4 w2 = *(const f32x4*)(w + (size_t)c4.z * DDIM + lane * 4);
    f32x4 w3 = *(const f32x4*)(w + (size_t)c4.w * DDIM + lane * 4);
    float p0 = fmaf(zv[0], w0[0], fmaf(zv[1], w0[1], fmaf(zv[2], w0[2], zv[3] * w0[3])));
    float p1 = fmaf(zv[0], w1[0], fmaf(zv[1], w1[1], fmaf(zv[2], w1[2], zv[3] * w1[3])));
    float p2 = fmaf(zv[0], w2[0], fmaf(zv[1], w2[1], fmaf(zv[2], w2[2], zv[3] * w2[3])));
    float p3 = fmaf(zv[0], w3[0], fmaf(zv[1], w3[1], fmaf(zv[2], w3[2], zv[3] * w3[3])));
#pragma unroll
    for (int m = 1; m <= 32; m <<= 1) {
      p0 += __shfl_xor(p0, m);
      p1 += __shfl_xor(p1, m);
      p2 += __shfl_xor(p2, m);
      p3 += __shfl_xor(p3, m);
    }
    float s0 = fmaf(-2.f, p0, wsq[c4.x]);
    float s1 = fmaf(-2.f, p1, wsq[c4.y]);
    float s2 = fmaf(-2.f, p2, wsq[c4.z]);
    float s3 = fmaf(-2.f, p3, wsq[c4.w]);
    float bs = s0; int bi = c4.x;
    if (s1 < bs || (s1 == bs && c4.y < bi)) { bs = s1; bi = c4.y; }
    if (s2 < bs || (s2 == bs && c4.z < bi)) { bs = s2; bi = c4.z; }
    if (s3 < bs || (s3 == bs && c4.w < bi)) { bs = s3; bi = c4.w; }
    if (bi != c4.x) {  // provisional was wrong: rewrite idx, z_q_st, loss delta
      f32x4 qn = *(const f32x4*)(w + (size_t)bi * DDIM + lane * 4);
      f32x4 o;
      float d2 = 0.f;
#pragma unroll
      for (int j = 0; j < 4; ++j) {
        float dfn = qn[j] - zv[j];
        float dfo = w0[j] - zv[j];
        o[j] = zv[j] + dfn;
        d2 += dfn * dfn - dfo * dfo;
      }
      *(f32x4*)(out + 1 + (size_t)r * DDIM + lane * 4) = o;
      if (lane == 0) out[(size_t)IDXOFF + r] = (float)bi;
      dloss += d2;
    }
  }
#pragma unroll
  for (int m = 1; m <= 32; m <<= 1) dloss += __shfl_xor(dloss, m);
  if (lane == 0 && dloss != 0.f) atomicAdd(&buckets[blockIdx.x & 63], dloss);
}

// ---------------- kernel 4: exact full rescan for list2 rows (expected ~0) ----------------
__global__ __launch_bounds__(256) void full_scan(
    const float* __restrict__ z, const float* __restrict__ w,
    const float* __restrict__ wsq, float* __restrict__ buckets,
    const int* __restrict__ cnt2, const int* __restrict__ list2,
    float* __restrict__ out) {
  __shared__ __align__(16) float zrow[DDIM];
  __shared__ float rv[256];
  __shared__ int ri[256];
  const int tid = threadIdx.x;
  const int n = *cnt2;
  for (int li = blockIdx.x; li < n; li += gridDim.x) {
    const int row = list2[li];
    __syncthreads();
    zrow[tid] = z[(size_t)row * DDIM + tid];
    __syncthreads();
    float bv = 3.4e38f; int bi = 0;
#pragma unroll
    for (int c0 = 0; c0 < 4; ++c0) {
      int c = tid * 4 + c0;
      const f32x4* wr4 = (const f32x4*)(w + (size_t)c * DDIM);
      const f32x4* zr4 = (const f32x4*)zrow;
      f32x4 dv = {0.f, 0.f, 0.f, 0.f};
      for (int q = 0; q < DDIM / 4; ++q) {
        f32x4 a = zr4[q], b = wr4[q];
        dv[0] = fmaf(a[0], b[0], dv[0]); dv[1] = fmaf(a[1], b[1], dv[1]);
        dv[2] = fmaf(a[2], b[2], dv[2]); dv[3] = fmaf(a[3], b[3], dv[3]);
      }
      float s = fmaf(-2.f, (dv[0] + dv[1]) + (dv[2] + dv[3]), wsq[c]);
      if (s < bv) { bv = s; bi = c; }   // c ascending per thread -> first-tie wins
    }
    rv[tid] = bv; ri[tid] = bi;
    __syncthreads();
    for (int s = 128; s > 0; s >>= 1) {
      if (tid < s) {
        float v2 = rv[tid + s]; int i2 = ri[tid + s];
        if (v2 < rv[tid] || (v2 == rv[tid] && i2 < ri[tid])) { rv[tid] = v2; ri[tid] = i2; }
      }
      __syncthreads();
    }
    const int idx = ri[0];
    const int old = (int)out[(size_t)IDXOFF + row];
    if (tid == 0) out[(size_t)IDXOFF + row] = (float)idx;
    float zv = zrow[tid];
    float dfn = w[(size_t)idx * DDIM + tid] - zv;
    float dfo = w[(size_t)old * DDIM + tid] - zv;
    out[1 + (size_t)row * DDIM + tid] = zv + dfn;
    __syncthreads();
    rv[tid] = dfn * dfn - dfo * dfo;
    __syncthreads();
    for (int s = 128; s > 0; s >>= 1) {
      if (tid < s) rv[tid] += rv[tid + s];
      __syncthreads();
    }
    if (tid == 0) atomicAdd(&buckets[row & 63], rv[0]);
  }
}

// ---------------- kernel 5: finalize loss ----------------
__global__ void vq_finalize(const float* __restrict__ buckets,
                            float* __restrict__ out) {
  float s = 0.f;
  for (int i = 0; i < 64; ++i) s += buckets[i];
  out[0] = 0.25f * s * (1.0f / 16777216.0f);
}

extern "C" void kernel_launch(void* const* d_in, const int* in_sizes, int n_in,
                              void* d_out, int out_size, void* d_ws, size_t ws_size,
                              hipStream_t stream) {
  const float* z = (const float*)d_in[0];
  const float* w = (const float*)d_in[1];
  float* out = (float*)d_out;
  float* wsf = (float*)d_ws;
  float* buckets = wsf;
  int* cnt = (int*)wsf + 64;
  int* cnt2 = (int*)wsf + 65;
  float* wsq = wsf + 80;
  float* wplanes = wsf + 2048;
  int* cand = (int*)(wsf + 264192);
  int* list = (int*)(wsf + 526336);
  int* list2 = (int*)(wsf + 591872);

  hipMemsetAsync(d_ws, 0, 320, stream);  // buckets + cnt + cnt2
  wsq_kernel<<<dim3(KCODES / 256), dim3(256), 0, stream>>>(w, wsq);
  prep_w<<<dim3(256), dim3(256), 0, stream>>>(w, wplanes);
  vq_main<<<dim3(NTOT / BRR), dim3(256), 0, stream>>>(z, w, wplanes, wsq, buckets,
                                                      cnt, cnt2, list, list2, cand, out);
  patch_lite<<<dim3(2048), dim3(256), 0, stream>>>(z, w, wsq, cnt, list, cand, buckets, out);
  full_scan<<<dim3(1024), dim3(256), 0, stream>>>(z, w, wsq, buckets, cnt2, list2, out);
  vq_finalize<<<dim3(1), dim3(1), 0, stream>>>(buckets, out);
}